// Round 5
// baseline (275.503 us; speedup 1.0000x reference)
//
#include <hip/hip_runtime.h>
#include <hip/hip_bf16.h>
#include <math.h>

// TriangleAttention: N=256, CZ=128, H=4, DH=32, fp32 in/out.
// Pipeline:
//   K0 convert_weights : wq|wk|wv|wg -> Wc_hi/lo [512,128] bf16, wo -> wo_hi/lo
//   K1 ln_tri          : LayerNorm + tri bias; xn emitted as bf16 hi/lo (in d_out!)
//                        tri stored PRE-TILED to the attn fragment layout
//   K2 gemm_direct<0>  : LDS-FREE split-bf16 MFMA GEMM (frags straight from
//                        global, zero barriers) -> q_bf, k_bf, vT_bf, g fp32
//   K3 attn_mfma       : per (i,h) MFMA attention, single-pass softmax
//   K4 gemm_direct<1>  : og @ wo^T + bo -> out fp32
// Orientation trick: for q/k/g/out use A=W,B=x (D rows = output-channel n,
// 4 consecutive n per lane -> packed stores); for vT use A=x,B=W (D rows = j).
// ws: tri 1MiB | g 33.5MiB | og_hi/lo 33.5MiB | q/k/vT bf16 50MiB | w 0.4MiB
// d_out doubles as xn_hi/lo scratch (dead before K4 writes it).

#define NN 256
#define CZ 128
#define NH 4
#define DH 32
#define NPOS (NN * NN)                  // 65536
#define PSZ ((size_t)NPOS * CZ)         // 8388608
#define SCALE 0.17677669529663687f      // 1/sqrt(32)

typedef unsigned short ushort_t;
using f32x4  = __attribute__((ext_vector_type(4))) float;
using bf16x8 = __attribute__((ext_vector_type(8))) short;   // 8 bf16 = 4 VGPRs
using bf16x4 = __attribute__((ext_vector_type(4))) short;   // 4 bf16 = 2 VGPRs

__device__ __forceinline__ float sigmoidf_(float x) {
    return 1.0f / (1.0f + __expf(-x));
}
__device__ __forceinline__ ushort_t f2bf(float f) {   // RNE float->bf16 bits
    unsigned u = __float_as_uint(f);
    u = (u + 0x7fffu + ((u >> 16) & 1u)) >> 16;
    return (ushort_t)u;
}
__device__ __forceinline__ float bf2f(ushort_t b) {
    return __uint_as_float(((unsigned)b) << 16);
}
__device__ __forceinline__ float trunc_bf(float f) {  // truncate mantissa to bf16
    return __uint_as_float(__float_as_uint(f) & 0xffff0000u);
}
__device__ __forceinline__ bf16x4 pack_bf4(float a, float b, float c, float d) {
    union { unsigned u[2]; bf16x4 v; } r;
    r.u[0] = (__float_as_uint(b) & 0xffff0000u) | (__float_as_uint(a) >> 16);
    r.u[1] = (__float_as_uint(d) & 0xffff0000u) | (__float_as_uint(c) >> 16);
    return r.v;
}
__device__ __forceinline__ bf16x4 pack_bf4_rne(float a, float b, float c, float d) {
    union { ushort_t s[4]; bf16x4 v; } r;
    r.s[0] = f2bf(a); r.s[1] = f2bf(b); r.s[2] = f2bf(c); r.s[3] = f2bf(d);
    return r.v;
}

// ---------------- K0: weight conversion ----------------
__global__ __launch_bounds__(256)
void convert_weights(const float* __restrict__ wq, const float* __restrict__ wk,
                     const float* __restrict__ wv, const float* __restrict__ wg,
                     const float* __restrict__ wo,
                     ushort_t* __restrict__ Wc_hi, ushort_t* __restrict__ Wc_lo,
                     ushort_t* __restrict__ wo_hi, ushort_t* __restrict__ wo_lo) {
    int idx = blockIdx.x * 256 + threadIdx.x;     // 0..81919
    float x;
    if (idx < 65536) {
        int t = idx >> 14;
        const float* src = (t == 0) ? wq : (t == 1) ? wk : (t == 2) ? wv : wg;
        x = src[idx & 16383];
        ushort_t h = f2bf(x);
        Wc_hi[idx] = h;
        Wc_lo[idx] = f2bf(x - bf2f(h));
    } else {
        int r = idx - 65536;                      // 0..16383
        x = wo[r];
        ushort_t h = f2bf(x);
        wo_hi[r] = h;
        wo_lo[r] = f2bf(x - bf2f(h));
    }
}

// ---------------- K1: LayerNorm + tri bias, xn -> bf16 hi/lo ----------------
__global__ __launch_bounds__(256)
void ln_tri_kernel(const float* __restrict__ x,
                   const float* __restrict__ ln_g,
                   const float* __restrict__ ln_b,
                   const float* __restrict__ w_tri,
                   ushort_t* __restrict__ xn_hi,
                   ushort_t* __restrict__ xn_lo,
                   float* __restrict__ tri) {
    int wave = threadIdx.x >> 6;
    int lane = threadIdx.x & 63;
    int p = blockIdx.x * 4 + wave;
    const float* xp = x + (size_t)p * CZ + lane * 2;
    float2 v = *(const float2*)xp;

    float s = v.x + v.y;
    float sq = v.x * v.x + v.y * v.y;
    #pragma unroll
    for (int off = 1; off < 64; off <<= 1) {
        s  += __shfl_xor(s,  off);
        sq += __shfl_xor(sq, off);
    }
    float mu = s * (1.0f / 128.0f);
    float var = sq * (1.0f / 128.0f) - mu * mu;
    float rs = rsqrtf(var + 1e-5f);

    float2 gv = *(const float2*)(ln_g + lane * 2);
    float2 bv = *(const float2*)(ln_b + lane * 2);
    float xn0 = (v.x - mu) * rs * gv.x + bv.x;
    float xn1 = (v.y - mu) * rs * gv.y + bv.y;

    ushort_t h0 = f2bf(xn0), h1 = f2bf(xn1);
    ushort_t l0 = f2bf(xn0 - bf2f(h0)), l1 = f2bf(xn1 - bf2f(h1));
    ushort2 hh; hh.x = h0; hh.y = h1;
    ushort2 ll; ll.x = l0; ll.y = l1;
    *(ushort2*)(xn_hi + (size_t)p * CZ + lane * 2) = hh;
    *(ushort2*)(xn_lo + (size_t)p * CZ + lane * 2) = ll;

    float t0, t1, t2, t3;
    {
        float2 w0 = *(const float2*)(w_tri + 0 * CZ + lane * 2);
        float2 w1 = *(const float2*)(w_tri + 1 * CZ + lane * 2);
        float2 w2 = *(const float2*)(w_tri + 2 * CZ + lane * 2);
        float2 w3 = *(const float2*)(w_tri + 3 * CZ + lane * 2);
        t0 = xn0 * w0.x + xn1 * w0.y;
        t1 = xn0 * w1.x + xn1 * w1.y;
        t2 = xn0 * w2.x + xn1 * w2.y;
        t3 = xn0 * w3.x + xn1 * w3.y;
    }
    #pragma unroll
    for (int off = 1; off < 64; off <<= 1) {
        t0 += __shfl_xor(t0, off);
        t1 += __shfl_xor(t1, off);
        t2 += __shfl_xor(t2, off);
        t3 += __shfl_xor(t3, off);
    }
    if (lane == 0) {
        int i = p >> 8, j = p & 255;     // q = i, key = j
        // pre-tiled layout: [h][kt][mt][wv][nt][kg*16+lr][r]
        int kt = j >> 6, mt = (j >> 4) & 3, kg2 = (j >> 2) & 3, r = j & 3;
        int wv2 = i >> 6, nt = (i >> 4) & 3, lr2 = i & 15;
        size_t base = ((((size_t)(kt * 16 + mt * 4 + wv2)) * 4 + nt) * 64 +
                       kg2 * 16 + lr2) * 4 + r;
        tri[base + 0 * 65536] = t0;
        tri[base + 1 * 65536] = t1;
        tri[base + 2 * 65536] = t2;
        tri[base + 3 * 65536] = t3;
    }
}

// ---------------- K2/K4: LDS-free split-bf16 MFMA GEMM ----------------
// out[m][n] = sum_k X[m][k]*W[n][k].  128x128 tile per block, 2x2 waves,
// K=128 in 4 steps of 32.  All fragments loaded straight from global (16B
// per lane); no LDS, no barriers.  Split-bf16: hh + lh + hl.
// MODE 0: W = Wc (t = blockIdx.y selects tensor); writes q/k/g (swapped
//         orientation, packed 8B/16B stores) and vT (normal orientation).
// MODE 1: W = wo; writes out fp32 + bias (swapped orientation, float4 stores).
template<int MODE>
__global__ __launch_bounds__(256)
void gemm_direct_kernel(const ushort_t* __restrict__ Xhi, const ushort_t* __restrict__ Xlo,
                        const ushort_t* __restrict__ Whi, const ushort_t* __restrict__ Wlo,
                        float* __restrict__ out0, const float* __restrict__ bias,
                        ushort_t* __restrict__ qbo, ushort_t* __restrict__ kbo,
                        ushort_t* __restrict__ vto, float* __restrict__ gfo) {
    const int tid = threadIdx.x;
    const int bm = blockIdx.x;
    const int t = (MODE == 0) ? blockIdx.y : 0;
    const int lane = tid & 63;
    const int wv_ = tid >> 6;
    const int wm = wv_ >> 1, wn = wv_ & 1;
    const int lr = lane & 15, kg = lane >> 4;

    // X-frag rows: m = bm*128 + wm*64 + mt*16 + lr
    // W-frag rows: n = t*128 + wn*64 + nt*16 + lr
    const ushort_t* xh_base = Xhi + ((size_t)(bm * 128 + wm * 64 + lr)) * CZ + kg * 8;
    const ushort_t* xl_base = Xlo + ((size_t)(bm * 128 + wm * 64 + lr)) * CZ + kg * 8;
    const ushort_t* wh_base = Whi + ((size_t)(t * 128 + wn * 64 + lr)) * CZ + kg * 8;
    const ushort_t* wl_base = Wlo + ((size_t)(t * 128 + wn * 64 + lr)) * CZ + kg * 8;

    f32x4 acc[4][4];    // swapped: acc[nt][mt]; normal (t==2): acc[mt][nt]
    #pragma unroll
    for (int a = 0; a < 4; a++)
        #pragma unroll
        for (int b = 0; b < 4; b++) acc[a][b] = (f32x4){0.f, 0.f, 0.f, 0.f};

    #pragma unroll
    for (int ks = 0; ks < 4; ks++) {
        bf16x8 xh[4], xl[4], wh[4], wl[4];
        #pragma unroll
        for (int mt = 0; mt < 4; mt++) {
            xh[mt] = *(const bf16x8*)(xh_base + (size_t)mt * 16 * CZ + ks * 32);
            xl[mt] = *(const bf16x8*)(xl_base + (size_t)mt * 16 * CZ + ks * 32);
        }
        #pragma unroll
        for (int nt = 0; nt < 4; nt++) {
            wh[nt] = *(const bf16x8*)(wh_base + (size_t)nt * 16 * CZ + ks * 32);
            wl[nt] = *(const bf16x8*)(wl_base + (size_t)nt * 16 * CZ + ks * 32);
        }
        if (MODE == 0 && t == 2) {
            // normal: A = X, B = W  (D rows = j, cols = d)
            #pragma unroll
            for (int mt = 0; mt < 4; mt++)
                #pragma unroll
                for (int nt = 0; nt < 4; nt++) {
                    acc[mt][nt] = __builtin_amdgcn_mfma_f32_16x16x32_bf16(xh[mt], wh[nt], acc[mt][nt], 0, 0, 0);
                    acc[mt][nt] = __builtin_amdgcn_mfma_f32_16x16x32_bf16(xl[mt], wh[nt], acc[mt][nt], 0, 0, 0);
                    acc[mt][nt] = __builtin_amdgcn_mfma_f32_16x16x32_bf16(xh[mt], wl[nt], acc[mt][nt], 0, 0, 0);
                }
        } else {
            // swapped: A = W, B = X  (D rows = n, cols = m)
            #pragma unroll
            for (int nt = 0; nt < 4; nt++)
                #pragma unroll
                for (int mt = 0; mt < 4; mt++) {
                    acc[nt][mt] = __builtin_amdgcn_mfma_f32_16x16x32_bf16(wh[nt], xh[mt], acc[nt][mt], 0, 0, 0);
                    acc[nt][mt] = __builtin_amdgcn_mfma_f32_16x16x32_bf16(wl[nt], xh[mt], acc[nt][mt], 0, 0, 0);
                    acc[nt][mt] = __builtin_amdgcn_mfma_f32_16x16x32_bf16(wh[nt], xl[mt], acc[nt][mt], 0, 0, 0);
                }
        }
    }

    if (MODE == 1) {
        // swapped: lane holds out rows m = bm*128+wm*64+mt*16+lr (col), 4
        // consecutive n = wn*64+nt*16+kg*4+r (rows) -> float4 stores.
        #pragma unroll
        for (int mt = 0; mt < 4; mt++) {
            int m = bm * 128 + wm * 64 + mt * 16 + lr;
            #pragma unroll
            for (int nt = 0; nt < 4; nt++) {
                int nb = wn * 64 + nt * 16 + kg * 4;
                float4 bv = *(const float4*)(bias + nb);
                float4 o;
                o.x = acc[nt][mt][0] + bv.x;
                o.y = acc[nt][mt][1] + bv.y;
                o.z = acc[nt][mt][2] + bv.z;
                o.w = acc[nt][mt][3] + bv.w;
                *(float4*)(out0 + (size_t)m * CZ + nb) = o;
            }
        }
    } else if (t == 2) {
        // normal: lane holds j rows = mt*16+kg*4+r (consecutive), d col = lr-ish
        #pragma unroll
        for (int mt = 0; mt < 4; mt++) {
            int m = bm * 128 + wm * 64 + mt * 16 + kg * 4;   // 4 consecutive j
            int i_ = m >> 8, jb = m & 255;
            #pragma unroll
            for (int nt = 0; nt < 4; nt++) {
                int n = wn * 64 + nt * 16 + lr;
                int h_ = n >> 5, d = n & 31;
                size_t ihb = (size_t)((i_ << 2) + h_) * 8192;
                *(bf16x4*)(vto + ihb + (size_t)d * 256 + jb) =
                    pack_bf4_rne(acc[mt][nt][0], acc[mt][nt][1], acc[mt][nt][2], acc[mt][nt][3]);
            }
        }
    } else {
        // swapped: lane holds j = mt*16+lr (col), 4 consecutive d (rows)
        #pragma unroll
        for (int mt = 0; mt < 4; mt++) {
            int m = bm * 128 + wm * 64 + mt * 16 + lr;
            int i_ = m >> 8, jj = m & 255;
            #pragma unroll
            for (int nt = 0; nt < 4; nt++) {
                int n = wn * 64 + nt * 16 + kg * 4;          // 4 consecutive
                int h_ = n >> 5, db = n & 31;
                size_t base = (size_t)((i_ << 2) + h_) * 8192 + (size_t)jj * 32 + db;
                if (t == 0) {
                    *(bf16x4*)(qbo + base) = pack_bf4_rne(
                        acc[nt][mt][0] * SCALE, acc[nt][mt][1] * SCALE,
                        acc[nt][mt][2] * SCALE, acc[nt][mt][3] * SCALE);
                } else if (t == 1) {
                    *(bf16x4*)(kbo + base) = pack_bf4_rne(
                        acc[nt][mt][0], acc[nt][mt][1], acc[nt][mt][2], acc[nt][mt][3]);
                } else {
                    float4 o;
                    o.x = acc[nt][mt][0]; o.y = acc[nt][mt][1];
                    o.z = acc[nt][mt][2]; o.w = acc[nt][mt][3];
                    *(float4*)(gfo + base) = o;
                }
            }
        }
    }
}

// ---------------- K3: MFMA attention, single-pass softmax ----------------
__global__ __launch_bounds__(256, 4)
void attn_mfma_kernel(const ushort_t* __restrict__ qb,
                      const ushort_t* __restrict__ kb,
                      const ushort_t* __restrict__ vtb,
                      const float* __restrict__ gf,
                      const float* __restrict__ tri,
                      const float* __restrict__ mask,
                      const float* __restrict__ bg,
                      ushort_t* __restrict__ og_hi,
                      ushort_t* __restrict__ og_lo) {
    __shared__ ushort_t sV[32 * 264];   // vT rows (d) stride 264 shorts

    const int bid = blockIdx.x;
    const int h = bid >> 8;
    const int i = bid & 255;
    const int tid = threadIdx.x;
    const int lane = tid & 63;
    const int wv_ = tid >> 6;
    const int lr = lane & 15;
    const int kg = lane >> 4;
    const int q0 = wv_ * 64;

    const size_t ih = (size_t)((i << 2) + h);
    const ushort_t* qp = qb + ih * 8192;
    const ushort_t* kp = kb + ih * 8192;
    const ushort_t* vp = vtb + ih * 8192;
    const float* mrow = mask + (i << 8);

    #pragma unroll
    for (int w = 0; w < 4; w++) {
        int idx = tid + w * 256;
        int d = idx >> 5, c = idx & 31;
        *(uint4*)&sV[d * 264 + c * 8] = *(const uint4*)(vp + d * 256 + c * 8);
    }

    bf16x8 qf[4];
    #pragma unroll
    for (int nt = 0; nt < 4; nt++)
        qf[nt] = *(const bf16x8*)(qp + (size_t)(q0 + nt * 16 + lr) * 32 + kg * 8);

    float tl[4] = {0.f, 0.f, 0.f, 0.f};
    f32x4 o[4][2];
    #pragma unroll
    for (int nt = 0; nt < 4; nt++) {
        o[nt][0] = (f32x4){0.f, 0.f, 0.f, 0.f};
        o[nt][1] = (f32x4){0.f, 0.f, 0.f, 0.f};
    }
    __syncthreads();

    for (int kt = 0; kt < 4; kt++) {
        const int kt0 = kt * 64;
        #pragma unroll
        for (int mt = 0; mt < 4; mt++) {
            bf16x8 ka = *(const bf16x8*)(kp + (size_t)(kt0 + mt * 16 + lr) * 32 + kg * 8);
            const float* trib = tri + ((size_t)h << 16) +
                                ((((size_t)(kt * 16 + mt * 4 + wv_)) * 4) * 64 +
                                 kg * 16 + lr) * 4;
            float4 trif[4];
            #pragma unroll
            for (int nt = 0; nt < 4; nt++)
                trif[nt] = *(const float4*)(trib + (size_t)nt * 256);
            float4 mq = *(const float4*)(mrow + kt0 + mt * 16 + kg * 4);
            float mb[4] = {(mq.x - 1.f) * 1e9f, (mq.y - 1.f) * 1e9f,
                           (mq.z - 1.f) * 1e9f, (mq.w - 1.f) * 1e9f};

            f32x4 st[4];
            #pragma unroll
            for (int nt = 0; nt < 4; nt++)
                st[nt] = __builtin_amdgcn_mfma_f32_16x16x32_bf16(
                    ka, qf[nt], (f32x4){0.f, 0.f, 0.f, 0.f}, 0, 0, 0);

            bf16x4 pa[4];
            #pragma unroll
            for (int nt = 0; nt < 4; nt++) {
                float p0 = trunc_bf(__expf(st[nt][0] + mb[0] + trif[nt].x));
                float p1 = trunc_bf(__expf(st[nt][1] + mb[1] + trif[nt].y));
                float p2 = trunc_bf(__expf(st[nt][2] + mb[2] + trif[nt].z));
                float p3 = trunc_bf(__expf(st[nt][3] + mb[3] + trif[nt].w));
                tl[nt] += (p0 + p1) + (p2 + p3);
                pa[nt] = pack_bf4(p0, p1, p2, p3);
            }
            #pragma unroll
            for (int dt = 0; dt < 2; dt++) {
                bf16x4 vb = *(const bf16x4*)&sV[(dt * 16 + lr) * 264 + kt0 + mt * 16 + kg * 4];
                #pragma unroll
                for (int nt = 0; nt < 4; nt++)
                    o[nt][dt] = __builtin_amdgcn_mfma_f32_16x16x16bf16_1k(pa[nt], vb, o[nt][dt], 0, 0, 0);
            }
        }
    }

    #pragma unroll
    for (int nt = 0; nt < 4; nt++) {
        float t = tl[nt];
        t += __shfl_xor(t, 16);
        t += __shfl_xor(t, 32);
        float inv = 1.0f / t;
        #pragma unroll
        for (int r = 0; r < 4; r++) {
            float iv = __shfl(inv, kg * 4 + r, 16);
            int q = q0 + nt * 16 + kg * 4 + r;
            #pragma unroll
            for (int dt = 0; dt < 2; dt++) {
                int d = dt * 16 + lr;
                float gate = sigmoidf_(gf[ih * 8192 + q * 32 + d] + bg[(h << 5) + d]);
                float val = o[nt][dt][r] * iv * gate;
                ushort_t vh = f2bf(val);
                ushort_t vl = f2bf(val - bf2f(vh));
                size_t ofs = (size_t)((i << 8) + q) * CZ + (h << 5) + d;
                og_hi[ofs] = vh;
                og_lo[ofs] = vl;
            }
        }
    }
}

extern "C" void kernel_launch(void* const* d_in, const int* in_sizes, int n_in,
                              void* d_out, int out_size, void* d_ws, size_t ws_size,
                              hipStream_t stream) {
    const float* x     = (const float*)d_in[0];
    const float* mask  = (const float*)d_in[1];
    const float* ln_g  = (const float*)d_in[2];
    const float* ln_b  = (const float*)d_in[3];
    const float* w_tri = (const float*)d_in[4];
    const float* wq    = (const float*)d_in[5];
    const float* wk    = (const float*)d_in[6];
    const float* wv    = (const float*)d_in[7];
    const float* wg    = (const float*)d_in[8];
    const float* bg    = (const float*)d_in[9];
    const float* wo    = (const float*)d_in[10];
    const float* bo    = (const float*)d_in[11];
    float* out = (float*)d_out;

    float* ws = (float*)d_ws;
    float* tri = ws;                              // 262144 f (pre-tiled)
    float* gf  = ws + 262144;                     // PSZ f
    ushort_t* og_hi = (ushort_t*)(gf + PSZ);      // PSZ us
    ushort_t* og_lo = og_hi + PSZ;
    ushort_t* qbuf  = og_lo + PSZ;
    ushort_t* kbuf  = qbuf + PSZ;
    ushort_t* vtbuf = kbuf + PSZ;
    ushort_t* Wc_hi = vtbuf + PSZ;
    ushort_t* Wc_lo = Wc_hi + 65536;
    ushort_t* wo_hi = Wc_lo + 65536;
    ushort_t* wo_lo = wo_hi + 16384;
    // xn hi/lo live in d_out (32 MiB, dead before K4 writes out)
    ushort_t* xn_hi = (ushort_t*)d_out;
    ushort_t* xn_lo = xn_hi + PSZ;

    convert_weights<<<320, 256, 0, stream>>>(wq, wk, wv, wg, wo, Wc_hi, Wc_lo, wo_hi, wo_lo);
    ln_tri_kernel<<<NPOS / 4, 256, 0, stream>>>(x, ln_g, ln_b, w_tri, xn_hi, xn_lo, tri);
    gemm_direct_kernel<0><<<dim3(NPOS / 128, 4), 256, 0, stream>>>(
        xn_hi, xn_lo, Wc_hi, Wc_lo, nullptr, nullptr, qbuf, kbuf, vtbuf, gf);
    attn_mfma_kernel<<<NN * NH, 256, 0, stream>>>(
        qbuf, kbuf, vtbuf, gf, tri, mask, bg, og_hi, og_lo);
    gemm_direct_kernel<1><<<dim3(NPOS / 128, 1), 256, 0, stream>>>(
        og_hi, og_lo, wo_hi, wo_lo, out, bo, nullptr, nullptr, nullptr, nullptr);
}

// Round 6
// 231.721 us; speedup vs baseline: 1.1889x; 1.1889x over previous
//
#include <hip/hip_runtime.h>
#include <hip/hip_bf16.h>
#include <math.h>

// TriangleAttention: N=256, CZ=128, H=4, DH=32, fp32 in/out.
// Pipeline:
//   K0 convert_weights : wq|wk|wv|wg -> Wc_hi/lo [512,128] bf16, wo -> wo_hi/lo
//   K1 ln_qkvg (FUSED) : per 64-position block: LayerNorm in registers ->
//                        xn bf16 hi/lo into LDS (never HBM) + tri bias (pre-tiled);
//                        one barrier; 4 waves = 4 tensors do split-bf16 MFMA GEMM
//                        with X-frags from LDS (conflict-free swizzle), W from L2.
//                        -> q_bf (pre-scaled), k_bf [i,h,j,d], vT_bf [i,h,d,j], g fp32
//   K2 attn_mfma       : per (i,h) MFMA attention, single-pass softmax
//   K3 gemm_direct<1>  : og @ wo^T + bo -> out fp32 (LDS-free direct GEMM)
// ws: tri 1MiB | g 33.5MiB | og_hi/lo 33.5MiB | q/k/vT bf16 50MiB | w 0.4MiB

#define NN 256
#define CZ 128
#define NH 4
#define DH 32
#define NPOS (NN * NN)                  // 65536
#define PSZ ((size_t)NPOS * CZ)         // 8388608
#define SCALE 0.17677669529663687f      // 1/sqrt(32)

typedef unsigned short ushort_t;
using f32x4  = __attribute__((ext_vector_type(4))) float;
using bf16x8 = __attribute__((ext_vector_type(8))) short;   // 8 bf16 = 4 VGPRs
using bf16x4 = __attribute__((ext_vector_type(4))) short;   // 4 bf16 = 2 VGPRs

__device__ __forceinline__ float sigmoidf_(float x) {
    return 1.0f / (1.0f + __expf(-x));
}
__device__ __forceinline__ ushort_t f2bf(float f) {   // RNE float->bf16 bits
    unsigned u = __float_as_uint(f);
    u = (u + 0x7fffu + ((u >> 16) & 1u)) >> 16;
    return (ushort_t)u;
}
__device__ __forceinline__ float bf2f(ushort_t b) {
    return __uint_as_float(((unsigned)b) << 16);
}
__device__ __forceinline__ float trunc_bf(float f) {  // truncate mantissa to bf16
    return __uint_as_float(__float_as_uint(f) & 0xffff0000u);
}
__device__ __forceinline__ bf16x4 pack_bf4(float a, float b, float c, float d) {
    union { unsigned u[2]; bf16x4 v; } r;
    r.u[0] = (__float_as_uint(b) & 0xffff0000u) | (__float_as_uint(a) >> 16);
    r.u[1] = (__float_as_uint(d) & 0xffff0000u) | (__float_as_uint(c) >> 16);
    return r.v;
}
__device__ __forceinline__ bf16x4 pack_bf4_rne(float a, float b, float c, float d) {
    union { ushort_t s[4]; bf16x4 v; } r;
    r.s[0] = f2bf(a); r.s[1] = f2bf(b); r.s[2] = f2bf(c); r.s[3] = f2bf(d);
    return r.v;
}

// swizzled LDS offset (shorts): row-major 64 shorts/row, 16B chunks XOR'd by row
#define SX(row, lc) ((row) * 64 + ((((lc) ^ ((row) & 7))) << 3))

// ---------------- K0: weight conversion ----------------
__global__ __launch_bounds__(256)
void convert_weights(const float* __restrict__ wq, const float* __restrict__ wk,
                     const float* __restrict__ wv, const float* __restrict__ wg,
                     const float* __restrict__ wo,
                     ushort_t* __restrict__ Wc_hi, ushort_t* __restrict__ Wc_lo,
                     ushort_t* __restrict__ wo_hi, ushort_t* __restrict__ wo_lo) {
    int idx = blockIdx.x * 256 + threadIdx.x;     // 0..81919
    float x;
    if (idx < 65536) {
        int t = idx >> 14;
        const float* src = (t == 0) ? wq : (t == 1) ? wk : (t == 2) ? wv : wg;
        x = src[idx & 16383];
        ushort_t h = f2bf(x);
        Wc_hi[idx] = h;
        Wc_lo[idx] = f2bf(x - bf2f(h));
    } else {
        int r = idx - 65536;                      // 0..16383
        x = wo[r];
        ushort_t h = f2bf(x);
        wo_hi[r] = h;
        wo_lo[r] = f2bf(x - bf2f(h));
    }
}

// ---------------- K1: FUSED LayerNorm + tri + QKVG GEMM ----------------
// Block: 64 positions (one i), 256 threads / 4 waves.
// Phase A: LN -> xn bf16 hi/lo in LDS + tri (pre-tiled [h][kt][mt][wv][nt][..][r]).
// Phase B: wave t computes tensor t (q/k/g swapped orientation, vT normal).
__global__ __launch_bounds__(256)
void ln_qkvg_kernel(const float* __restrict__ x,
                    const float* __restrict__ ln_g,
                    const float* __restrict__ ln_b,
                    const float* __restrict__ w_tri,
                    const ushort_t* __restrict__ Wc_hi,
                    const ushort_t* __restrict__ Wc_lo,
                    float* __restrict__ tri,
                    ushort_t* __restrict__ qbo, ushort_t* __restrict__ kbo,
                    ushort_t* __restrict__ vto, float* __restrict__ gfo) {
    __shared__ ushort_t sXh[2][64 * 64];   // [cz-half][row 64][64 shorts swizzled]
    __shared__ ushort_t sXl[2][64 * 64];

    const int tid = threadIdx.x;
    const int p0 = blockIdx.x * 64;        // 64 positions, all same i
    const int g16 = tid >> 4;              // 0..15 row slot
    const int cg  = tid & 15;              // 8-channel group

    // ---- Phase A: LayerNorm (4 passes x 16 rows) ----
    float4 gv0 = *(const float4*)(ln_g + cg * 8);
    float4 gv1 = *(const float4*)(ln_g + cg * 8 + 4);
    float4 bv0 = *(const float4*)(ln_b + cg * 8);
    float4 bv1 = *(const float4*)(ln_b + cg * 8 + 4);
    float wtf[4][8];
    #pragma unroll
    for (int h = 0; h < 4; h++) {
        float4 w0 = *(const float4*)(w_tri + h * CZ + cg * 8);
        float4 w1 = *(const float4*)(w_tri + h * CZ + cg * 8 + 4);
        wtf[h][0] = w0.x; wtf[h][1] = w0.y; wtf[h][2] = w0.z; wtf[h][3] = w0.w;
        wtf[h][4] = w1.x; wtf[h][5] = w1.y; wtf[h][6] = w1.z; wtf[h][7] = w1.w;
    }
    float gg[8] = {gv0.x, gv0.y, gv0.z, gv0.w, gv1.x, gv1.y, gv1.z, gv1.w};
    float bb[8] = {bv0.x, bv0.y, bv0.z, bv0.w, bv1.x, bv1.y, bv1.z, bv1.w};

    #pragma unroll
    for (int pp = 0; pp < 4; pp++) {
        int row = pp * 16 + g16;
        const float* xp = x + (size_t)(p0 + row) * CZ + cg * 8;
        float4 a = *(const float4*)xp;
        float4 b = *(const float4*)(xp + 4);
        float xv[8] = {a.x, a.y, a.z, a.w, b.x, b.y, b.z, b.w};
        float s = 0.f, sq = 0.f;
        #pragma unroll
        for (int e = 0; e < 8; e++) { s += xv[e]; sq += xv[e] * xv[e]; }
        #pragma unroll
        for (int off = 1; off < 16; off <<= 1) {
            s  += __shfl_xor(s,  off);
            sq += __shfl_xor(sq, off);
        }
        float mu = s * (1.0f / 128.0f);
        float var = sq * (1.0f / 128.0f) - mu * mu;
        float rs = rsqrtf(var + 1e-5f);

        float xn[8];
        float t0 = 0.f, t1 = 0.f, t2 = 0.f, t3 = 0.f;
        union { ushort_t sv[8]; uint4 u; } H, L;
        #pragma unroll
        for (int e = 0; e < 8; e++) {
            xn[e] = (xv[e] - mu) * rs * gg[e] + bb[e];
            H.sv[e] = f2bf(xn[e]);
            L.sv[e] = f2bf(xn[e] - bf2f(H.sv[e]));
            t0 += xn[e] * wtf[0][e];
            t1 += xn[e] * wtf[1][e];
            t2 += xn[e] * wtf[2][e];
            t3 += xn[e] * wtf[3][e];
        }
        *(uint4*)&sXh[cg >> 3][SX(row, cg & 7)] = H.u;
        *(uint4*)&sXl[cg >> 3][SX(row, cg & 7)] = L.u;

        #pragma unroll
        for (int off = 1; off < 16; off <<= 1) {
            t0 += __shfl_xor(t0, off);
            t1 += __shfl_xor(t1, off);
            t2 += __shfl_xor(t2, off);
            t3 += __shfl_xor(t3, off);
        }
        if (cg == 0) {
            int p = p0 + row;
            int i = p >> 8, j = p & 255;   // q = i, key = j
            int kt = j >> 6, mt = (j >> 4) & 3, kg2 = (j >> 2) & 3, r = j & 3;
            int wv2 = i >> 6, nt = (i >> 4) & 3, lr2 = i & 15;
            size_t base = ((((size_t)(kt * 16 + mt * 4 + wv2)) * 4 + nt) * 64 +
                           kg2 * 16 + lr2) * 4 + r;
            tri[base + 0 * 65536] = t0;
            tri[base + 1 * 65536] = t1;
            tri[base + 2 * 65536] = t2;
            tri[base + 3 * 65536] = t3;
        }
    }
    __syncthreads();

    // ---- Phase B: GEMM, wave = tensor ----
    const int lane = tid & 63;
    const int t = tid >> 6;                 // tensor 0=q 1=k 2=vT 3=g
    const int lr = lane & 15, kg = lane >> 4;
    const int i_ = p0 >> 8;
    const int j0 = p0 & 255;

    const ushort_t* whb = Wc_hi + ((size_t)(t * 128 + lr)) * CZ + kg * 8;
    const ushort_t* wlb = Wc_lo + ((size_t)(t * 128 + lr)) * CZ + kg * 8;

    #pragma unroll
    for (int np = 0; np < 2; np++) {        // N halves (64 channels each)
        f32x4 acc[4][4];
        #pragma unroll
        for (int a = 0; a < 4; a++)
            #pragma unroll
            for (int b = 0; b < 4; b++) acc[a][b] = (f32x4){0.f, 0.f, 0.f, 0.f};

        #pragma unroll
        for (int ks = 0; ks < 4; ks++) {
            bf16x8 xh[4], xl[4];
            #pragma unroll
            for (int mt = 0; mt < 4; mt++) {
                xh[mt] = *(bf16x8*)&sXh[ks >> 1][SX(mt * 16 + lr, (ks & 1) * 4 + kg)];
                xl[mt] = *(bf16x8*)&sXl[ks >> 1][SX(mt * 16 + lr, (ks & 1) * 4 + kg)];
            }
            #pragma unroll
            for (int nt = 0; nt < 4; nt++) {
                int n = np * 64 + nt * 16;
                bf16x8 wh = *(const bf16x8*)(whb + (size_t)n * CZ + ks * 32);
                bf16x8 wl = *(const bf16x8*)(wlb + (size_t)n * CZ + ks * 32);
                if (t == 2) {
                    // normal: A = X (rows = pos), B = W (cols = channel)
                    #pragma unroll
                    for (int mt = 0; mt < 4; mt++) {
                        acc[mt][nt] = __builtin_amdgcn_mfma_f32_16x16x32_bf16(xh[mt], wh, acc[mt][nt], 0, 0, 0);
                        acc[mt][nt] = __builtin_amdgcn_mfma_f32_16x16x32_bf16(xl[mt], wh, acc[mt][nt], 0, 0, 0);
                        acc[mt][nt] = __builtin_amdgcn_mfma_f32_16x16x32_bf16(xh[mt], wl, acc[mt][nt], 0, 0, 0);
                    }
                } else {
                    // swapped: A = W (rows = channel), B = X (cols = pos)
                    #pragma unroll
                    for (int mt = 0; mt < 4; mt++) {
                        acc[nt][mt] = __builtin_amdgcn_mfma_f32_16x16x32_bf16(wh, xh[mt], acc[nt][mt], 0, 0, 0);
                        acc[nt][mt] = __builtin_amdgcn_mfma_f32_16x16x32_bf16(wh, xl[mt], acc[nt][mt], 0, 0, 0);
                        acc[nt][mt] = __builtin_amdgcn_mfma_f32_16x16x32_bf16(wl, xh[mt], acc[nt][mt], 0, 0, 0);
                    }
                }
            }
        }

        // epilogue for this channel half
        if (t == 2) {
            // D rows = pos (kg*4+r consecutive), cols = channel (nt*16+lr)
            #pragma unroll
            for (int mt = 0; mt < 4; mt++) {
                int j = j0 + mt * 16 + kg * 4;      // 4 consecutive positions
                #pragma unroll
                for (int nt = 0; nt < 4; nt++) {
                    int c = np * 64 + nt * 16 + lr;
                    int h = c >> 5, d = c & 31;
                    size_t ihb = (size_t)((i_ << 2) + h) * 8192;
                    *(bf16x4*)(vto + ihb + (size_t)d * 256 + j) =
                        pack_bf4_rne(acc[mt][nt][0], acc[mt][nt][1],
                                     acc[mt][nt][2], acc[mt][nt][3]);
                }
            }
        } else {
            // D rows = channel (kg*4+r consecutive), cols = pos (mt*16+lr)
            #pragma unroll
            for (int mt = 0; mt < 4; mt++) {
                int j = j0 + mt * 16 + lr;
                #pragma unroll
                for (int nt = 0; nt < 4; nt++) {
                    int c = np * 64 + nt * 16 + kg * 4;  // 4 consecutive channels
                    int h = c >> 5, d = c & 31;
                    size_t base = (size_t)((i_ << 2) + h) * 8192 + (size_t)j * 32 + d;
                    if (t == 0) {
                        *(bf16x4*)(qbo + base) = pack_bf4_rne(
                            acc[nt][mt][0] * SCALE, acc[nt][mt][1] * SCALE,
                            acc[nt][mt][2] * SCALE, acc[nt][mt][3] * SCALE);
                    } else if (t == 1) {
                        *(bf16x4*)(kbo + base) = pack_bf4_rne(
                            acc[nt][mt][0], acc[nt][mt][1],
                            acc[nt][mt][2], acc[nt][mt][3]);
                    } else {
                        float4 o;
                        o.x = acc[nt][mt][0]; o.y = acc[nt][mt][1];
                        o.z = acc[nt][mt][2]; o.w = acc[nt][mt][3];
                        *(float4*)(gfo + base) = o;
                    }
                }
            }
        }
    }
}

// ---------------- K3(old K4): LDS-free split-bf16 direct GEMM (out-proj) ----------------
__global__ __launch_bounds__(256)
void gemm_direct_kernel(const ushort_t* __restrict__ Xhi, const ushort_t* __restrict__ Xlo,
                        const ushort_t* __restrict__ Whi, const ushort_t* __restrict__ Wlo,
                        float* __restrict__ out0, const float* __restrict__ bias) {
    const int tid = threadIdx.x;
    const int bm = blockIdx.x;
    const int lane = tid & 63;
    const int wv_ = tid >> 6;
    const int wm = wv_ >> 1, wn = wv_ & 1;
    const int lr = lane & 15, kg = lane >> 4;

    const ushort_t* xh_base = Xhi + ((size_t)(bm * 128 + wm * 64 + lr)) * CZ + kg * 8;
    const ushort_t* xl_base = Xlo + ((size_t)(bm * 128 + wm * 64 + lr)) * CZ + kg * 8;
    const ushort_t* wh_base = Whi + ((size_t)(wn * 64 + lr)) * CZ + kg * 8;
    const ushort_t* wl_base = Wlo + ((size_t)(wn * 64 + lr)) * CZ + kg * 8;

    f32x4 acc[4][4];   // [nt][mt], swapped orientation
    #pragma unroll
    for (int a = 0; a < 4; a++)
        #pragma unroll
        for (int b = 0; b < 4; b++) acc[a][b] = (f32x4){0.f, 0.f, 0.f, 0.f};

    #pragma unroll
    for (int ks = 0; ks < 4; ks++) {
        bf16x8 xh[4], xl[4], wh[4], wl[4];
        #pragma unroll
        for (int mt = 0; mt < 4; mt++) {
            xh[mt] = *(const bf16x8*)(xh_base + (size_t)mt * 16 * CZ + ks * 32);
            xl[mt] = *(const bf16x8*)(xl_base + (size_t)mt * 16 * CZ + ks * 32);
        }
        #pragma unroll
        for (int nt = 0; nt < 4; nt++) {
            wh[nt] = *(const bf16x8*)(wh_base + (size_t)nt * 16 * CZ + ks * 32);
            wl[nt] = *(const bf16x8*)(wl_base + (size_t)nt * 16 * CZ + ks * 32);
        }
        #pragma unroll
        for (int nt = 0; nt < 4; nt++)
            #pragma unroll
            for (int mt = 0; mt < 4; mt++) {
                acc[nt][mt] = __builtin_amdgcn_mfma_f32_16x16x32_bf16(wh[nt], xh[mt], acc[nt][mt], 0, 0, 0);
                acc[nt][mt] = __builtin_amdgcn_mfma_f32_16x16x32_bf16(wl[nt], xh[mt], acc[nt][mt], 0, 0, 0);
                acc[nt][mt] = __builtin_amdgcn_mfma_f32_16x16x32_bf16(wh[nt], xl[mt], acc[nt][mt], 0, 0, 0);
            }
    }

    #pragma unroll
    for (int mt = 0; mt < 4; mt++) {
        int m = bm * 128 + wm * 64 + mt * 16 + lr;
        #pragma unroll
        for (int nt = 0; nt < 4; nt++) {
            int nb = wn * 64 + nt * 16 + kg * 4;
            float4 bv = *(const float4*)(bias + nb);
            float4 o;
            o.x = acc[nt][mt][0] + bv.x;
            o.y = acc[nt][mt][1] + bv.y;
            o.z = acc[nt][mt][2] + bv.z;
            o.w = acc[nt][mt][3] + bv.w;
            *(float4*)(out0 + (size_t)m * CZ + nb) = o;
        }
    }
}

// ---------------- K2: MFMA attention, single-pass softmax ----------------
__global__ __launch_bounds__(256, 4)
void attn_mfma_kernel(const ushort_t* __restrict__ qb,
                      const ushort_t* __restrict__ kb,
                      const ushort_t* __restrict__ vtb,
                      const float* __restrict__ gf,
                      const float* __restrict__ tri,
                      const float* __restrict__ mask,
                      const float* __restrict__ bg,
                      ushort_t* __restrict__ og_hi,
                      ushort_t* __restrict__ og_lo) {
    __shared__ ushort_t sV[32 * 264];   // vT rows (d) stride 264 shorts

    const int bid = blockIdx.x;
    const int h = bid >> 8;
    const int i = bid & 255;
    const int tid = threadIdx.x;
    const int lane = tid & 63;
    const int wv_ = tid >> 6;
    const int lr = lane & 15;
    const int kg = lane >> 4;
    const int q0 = wv_ * 64;

    const size_t ih = (size_t)((i << 2) + h);
    const ushort_t* qp = qb + ih * 8192;
    const ushort_t* kp = kb + ih * 8192;
    const ushort_t* vp = vtb + ih * 8192;
    const float* mrow = mask + (i << 8);

    #pragma unroll
    for (int w = 0; w < 4; w++) {
        int idx = tid + w * 256;
        int d = idx >> 5, c = idx & 31;
        *(uint4*)&sV[d * 264 + c * 8] = *(const uint4*)(vp + d * 256 + c * 8);
    }

    bf16x8 qf[4];
    #pragma unroll
    for (int nt = 0; nt < 4; nt++)
        qf[nt] = *(const bf16x8*)(qp + (size_t)(q0 + nt * 16 + lr) * 32 + kg * 8);

    float tl[4] = {0.f, 0.f, 0.f, 0.f};
    f32x4 o[4][2];
    #pragma unroll
    for (int nt = 0; nt < 4; nt++) {
        o[nt][0] = (f32x4){0.f, 0.f, 0.f, 0.f};
        o[nt][1] = (f32x4){0.f, 0.f, 0.f, 0.f};
    }
    __syncthreads();

    #pragma unroll
    for (int kt = 0; kt < 4; kt++) {
        const int kt0 = kt * 64;
        #pragma unroll
        for (int mt = 0; mt < 4; mt++) {
            bf16x8 ka = *(const bf16x8*)(kp + (size_t)(kt0 + mt * 16 + lr) * 32 + kg * 8);
            const float* trib = tri + ((size_t)h << 16) +
                                ((((size_t)(kt * 16 + mt * 4 + wv_)) * 4) * 64 +
                                 kg * 16 + lr) * 4;
            float4 trif[4];
            #pragma unroll
            for (int nt = 0; nt < 4; nt++)
                trif[nt] = *(const float4*)(trib + (size_t)nt * 256);
            float4 mq = *(const float4*)(mrow + kt0 + mt * 16 + kg * 4);
            float mb[4] = {(mq.x - 1.f) * 1e9f, (mq.y - 1.f) * 1e9f,
                           (mq.z - 1.f) * 1e9f, (mq.w - 1.f) * 1e9f};

            f32x4 st[4];
            #pragma unroll
            for (int nt = 0; nt < 4; nt++)
                st[nt] = __builtin_amdgcn_mfma_f32_16x16x32_bf16(
                    ka, qf[nt], (f32x4){0.f, 0.f, 0.f, 0.f}, 0, 0, 0);

            bf16x4 pa[4];
            #pragma unroll
            for (int nt = 0; nt < 4; nt++) {
                float p0 = trunc_bf(__expf(st[nt][0] + mb[0] + trif[nt].x));
                float p1 = trunc_bf(__expf(st[nt][1] + mb[1] + trif[nt].y));
                float p2 = trunc_bf(__expf(st[nt][2] + mb[2] + trif[nt].z));
                float p3 = trunc_bf(__expf(st[nt][3] + mb[3] + trif[nt].w));
                tl[nt] += (p0 + p1) + (p2 + p3);
                pa[nt] = pack_bf4(p0, p1, p2, p3);
            }
            #pragma unroll
            for (int dt = 0; dt < 2; dt++) {
                bf16x4 vb = *(const bf16x4*)&sV[(dt * 16 + lr) * 264 + kt0 + mt * 16 + kg * 4];
                #pragma unroll
                for (int nt = 0; nt < 4; nt++)
                    o[nt][dt] = __builtin_amdgcn_mfma_f32_16x16x16bf16_1k(pa[nt], vb, o[nt][dt], 0, 0, 0);
            }
        }
    }

    #pragma unroll
    for (int nt = 0; nt < 4; nt++) {
        float t = tl[nt];
        t += __shfl_xor(t, 16);
        t += __shfl_xor(t, 32);
        float inv = 1.0f / t;
        #pragma unroll
        for (int r = 0; r < 4; r++) {
            float iv = __shfl(inv, kg * 4 + r, 16);
            int q = q0 + nt * 16 + kg * 4 + r;
            #pragma unroll
            for (int dt = 0; dt < 2; dt++) {
                int d = dt * 16 + lr;
                float gate = sigmoidf_(gf[ih * 8192 + q * 32 + d] + bg[(h << 5) + d]);
                float val = o[nt][dt][r] * iv * gate;
                ushort_t vh = f2bf(val);
                ushort_t vl = f2bf(val - bf2f(vh));
                size_t ofs = (size_t)((i << 8) + q) * CZ + (h << 5) + d;
                og_hi[ofs] = vh;
                og_lo[ofs] = vl;
            }
        }
    }
}

extern "C" void kernel_launch(void* const* d_in, const int* in_sizes, int n_in,
                              void* d_out, int out_size, void* d_ws, size_t ws_size,
                              hipStream_t stream) {
    const float* x     = (const float*)d_in[0];
    const float* mask  = (const float*)d_in[1];
    const float* ln_g  = (const float*)d_in[2];
    const float* ln_b  = (const float*)d_in[3];
    const float* w_tri = (const float*)d_in[4];
    const float* wq    = (const float*)d_in[5];
    const float* wk    = (const float*)d_in[6];
    const float* wv    = (const float*)d_in[7];
    const float* wg    = (const float*)d_in[8];
    const float* bg    = (const float*)d_in[9];
    const float* wo    = (const float*)d_in[10];
    const float* bo    = (const float*)d_in[11];
    float* out = (float*)d_out;

    float* ws = (float*)d_ws;
    float* tri = ws;                              // 262144 f (pre-tiled)
    float* gf  = ws + 262144;                     // PSZ f
    ushort_t* og_hi = (ushort_t*)(gf + PSZ);      // PSZ us
    ushort_t* og_lo = og_hi + PSZ;
    ushort_t* qbuf  = og_lo + PSZ;
    ushort_t* kbuf  = qbuf + PSZ;
    ushort_t* vtbuf = kbuf + PSZ;
    ushort_t* Wc_hi = vtbuf + PSZ;
    ushort_t* Wc_lo = Wc_hi + 65536;
    ushort_t* wo_hi = Wc_lo + 65536;
    ushort_t* wo_lo = wo_hi + 16384;

    convert_weights<<<320, 256, 0, stream>>>(wq, wk, wv, wg, wo, Wc_hi, Wc_lo, wo_hi, wo_lo);
    ln_qkvg_kernel<<<NPOS / 64, 256, 0, stream>>>(
        x, ln_g, ln_b, w_tri, Wc_hi, Wc_lo, tri, qbuf, kbuf, vtbuf, gf);
    attn_mfma_kernel<<<NN * NH, 256, 0, stream>>>(
        qbuf, kbuf, vtbuf, gf, tri, mask, bg, og_hi, og_lo);
    gemm_direct_kernel<<<NPOS / 128, 256, 0, stream>>>(
        og_hi, og_lo, wo_hi, wo_lo, out, bo);
}

// Round 7
// 210.072 us; speedup vs baseline: 1.3115x; 1.1031x over previous
//
#include <hip/hip_runtime.h>
#include <hip/hip_bf16.h>
#include <math.h>

// TriangleAttention: N=256, CZ=128, H=4, DH=32, fp32 in/out.
// Pipeline:
//   K0 convert_weights : wq|wk|wv|wg -> Wc_hi/lo [512,128] bf16, wo -> wo_hi/lo
//   K1 ln_qkvg (FUSED) : LayerNorm in regs -> xn bf16 hi/lo in LDS + tri (pre-tiled);
//                        4 waves = 4 tensors split-bf16 MFMA -> q_bf, k_bf, vT_bf,
//                        g fp16 [i,h,j,d]
//   K2 attn_out (FUSED): block = (i, q-chunk 64), 4 waves = 4 heads.
//                        Per wave: single-pass-softmax MFMA attention (vT frags
//                        straight from global/L2); gated og -> LDS bf16 hi/lo;
//                        one barrier; 4 waves do out-proj og@wo^T+bo from LDS.
//                        NO og HBM round-trip, no separate out-proj kernel.
// ws: tri 1MiB | g fp16 16MiB | q/k/vT bf16 48MiB | w 0.4MiB

#define NN 256
#define CZ 128
#define NH 4
#define DH 32
#define NPOS (NN * NN)                  // 65536
#define PSZ ((size_t)NPOS * CZ)         // 8388608
#define SCALE 0.17677669529663687f      // 1/sqrt(32)

typedef unsigned short ushort_t;
using f32x4  = __attribute__((ext_vector_type(4))) float;
using bf16x8 = __attribute__((ext_vector_type(8))) short;   // 8 bf16 = 4 VGPRs
using bf16x4 = __attribute__((ext_vector_type(4))) short;   // 4 bf16 = 2 VGPRs

__device__ __forceinline__ float sigmoidf_(float x) {
    return 1.0f / (1.0f + __expf(-x));
}
__device__ __forceinline__ ushort_t f2bf(float f) {   // RNE float->bf16 bits
    unsigned u = __float_as_uint(f);
    u = (u + 0x7fffu + ((u >> 16) & 1u)) >> 16;
    return (ushort_t)u;
}
__device__ __forceinline__ float bf2f(ushort_t b) {
    return __uint_as_float(((unsigned)b) << 16);
}
__device__ __forceinline__ float trunc_bf(float f) {  // truncate mantissa to bf16
    return __uint_as_float(__float_as_uint(f) & 0xffff0000u);
}
__device__ __forceinline__ ushort_t f2h(float f) {    // fp32 -> fp16 bits (RNE)
    _Float16 h = (_Float16)f;
    union { _Float16 h; ushort_t u; } c; c.h = h; return c.u;
}
__device__ __forceinline__ float h2f(ushort_t u) {
    union { ushort_t u; _Float16 h; } c; c.u = u; return (float)c.h;
}
__device__ __forceinline__ bf16x4 pack_bf4(float a, float b, float c, float d) {
    union { unsigned u[2]; bf16x4 v; } r;
    r.u[0] = (__float_as_uint(b) & 0xffff0000u) | (__float_as_uint(a) >> 16);
    r.u[1] = (__float_as_uint(d) & 0xffff0000u) | (__float_as_uint(c) >> 16);
    return r.v;
}
__device__ __forceinline__ bf16x4 pack_bf4_rne(float a, float b, float c, float d) {
    union { ushort_t s[4]; bf16x4 v; } r;
    r.s[0] = f2bf(a); r.s[1] = f2bf(b); r.s[2] = f2bf(c); r.s[3] = f2bf(d);
    return r.v;
}

// swizzled LDS offset (shorts): row-major 64 shorts/row, 16B chunks XOR'd by row
#define SX(row, lc) ((row) * 64 + ((((lc) ^ ((row) & 7))) << 3))

// ---------------- K0: weight conversion ----------------
__global__ __launch_bounds__(256)
void convert_weights(const float* __restrict__ wq, const float* __restrict__ wk,
                     const float* __restrict__ wv, const float* __restrict__ wg,
                     const float* __restrict__ wo,
                     ushort_t* __restrict__ Wc_hi, ushort_t* __restrict__ Wc_lo,
                     ushort_t* __restrict__ wo_hi, ushort_t* __restrict__ wo_lo) {
    int idx = blockIdx.x * 256 + threadIdx.x;     // 0..81919
    float x;
    if (idx < 65536) {
        int t = idx >> 14;
        const float* src = (t == 0) ? wq : (t == 1) ? wk : (t == 2) ? wv : wg;
        x = src[idx & 16383];
        ushort_t h = f2bf(x);
        Wc_hi[idx] = h;
        Wc_lo[idx] = f2bf(x - bf2f(h));
    } else {
        int r = idx - 65536;                      // 0..16383
        x = wo[r];
        ushort_t h = f2bf(x);
        wo_hi[r] = h;
        wo_lo[r] = f2bf(x - bf2f(h));
    }
}

// ---------------- K1: FUSED LayerNorm + tri + QKVG GEMM ----------------
__global__ __launch_bounds__(256)
void ln_qkvg_kernel(const float* __restrict__ x,
                    const float* __restrict__ ln_g,
                    const float* __restrict__ ln_b,
                    const float* __restrict__ w_tri,
                    const ushort_t* __restrict__ Wc_hi,
                    const ushort_t* __restrict__ Wc_lo,
                    float* __restrict__ tri,
                    ushort_t* __restrict__ qbo, ushort_t* __restrict__ kbo,
                    ushort_t* __restrict__ vto, ushort_t* __restrict__ gho) {
    __shared__ ushort_t sXh[2][64 * 64];
    __shared__ ushort_t sXl[2][64 * 64];

    const int tid = threadIdx.x;
    const int p0 = blockIdx.x * 64;
    const int g16 = tid >> 4;
    const int cg  = tid & 15;

    float4 gv0 = *(const float4*)(ln_g + cg * 8);
    float4 gv1 = *(const float4*)(ln_g + cg * 8 + 4);
    float4 bv0 = *(const float4*)(ln_b + cg * 8);
    float4 bv1 = *(const float4*)(ln_b + cg * 8 + 4);
    float wtf[4][8];
    #pragma unroll
    for (int h = 0; h < 4; h++) {
        float4 w0 = *(const float4*)(w_tri + h * CZ + cg * 8);
        float4 w1 = *(const float4*)(w_tri + h * CZ + cg * 8 + 4);
        wtf[h][0] = w0.x; wtf[h][1] = w0.y; wtf[h][2] = w0.z; wtf[h][3] = w0.w;
        wtf[h][4] = w1.x; wtf[h][5] = w1.y; wtf[h][6] = w1.z; wtf[h][7] = w1.w;
    }
    float gg[8] = {gv0.x, gv0.y, gv0.z, gv0.w, gv1.x, gv1.y, gv1.z, gv1.w};
    float bb[8] = {bv0.x, bv0.y, bv0.z, bv0.w, bv1.x, bv1.y, bv1.z, bv1.w};

    #pragma unroll
    for (int pp = 0; pp < 4; pp++) {
        int row = pp * 16 + g16;
        const float* xp = x + (size_t)(p0 + row) * CZ + cg * 8;
        float4 a = *(const float4*)xp;
        float4 b = *(const float4*)(xp + 4);
        float xv[8] = {a.x, a.y, a.z, a.w, b.x, b.y, b.z, b.w};
        float s = 0.f, sq = 0.f;
        #pragma unroll
        for (int e = 0; e < 8; e++) { s += xv[e]; sq += xv[e] * xv[e]; }
        #pragma unroll
        for (int off = 1; off < 16; off <<= 1) {
            s  += __shfl_xor(s,  off);
            sq += __shfl_xor(sq, off);
        }
        float mu = s * (1.0f / 128.0f);
        float var = sq * (1.0f / 128.0f) - mu * mu;
        float rs = rsqrtf(var + 1e-5f);

        float xn[8];
        float t0 = 0.f, t1 = 0.f, t2 = 0.f, t3 = 0.f;
        union { ushort_t sv[8]; uint4 u; } H, L;
        #pragma unroll
        for (int e = 0; e < 8; e++) {
            xn[e] = (xv[e] - mu) * rs * gg[e] + bb[e];
            H.sv[e] = f2bf(xn[e]);
            L.sv[e] = f2bf(xn[e] - bf2f(H.sv[e]));
            t0 += xn[e] * wtf[0][e];
            t1 += xn[e] * wtf[1][e];
            t2 += xn[e] * wtf[2][e];
            t3 += xn[e] * wtf[3][e];
        }
        *(uint4*)&sXh[cg >> 3][SX(row, cg & 7)] = H.u;
        *(uint4*)&sXl[cg >> 3][SX(row, cg & 7)] = L.u;

        #pragma unroll
        for (int off = 1; off < 16; off <<= 1) {
            t0 += __shfl_xor(t0, off);
            t1 += __shfl_xor(t1, off);
            t2 += __shfl_xor(t2, off);
            t3 += __shfl_xor(t3, off);
        }
        if (cg == 0) {
            int p = p0 + row;
            int i = p >> 8, j = p & 255;
            int kt = j >> 6, mt = (j >> 4) & 3, kg2 = (j >> 2) & 3, r = j & 3;
            int wv2 = i >> 6, nt = (i >> 4) & 3, lr2 = i & 15;
            size_t base = ((((size_t)(kt * 16 + mt * 4 + wv2)) * 4 + nt) * 64 +
                           kg2 * 16 + lr2) * 4 + r;
            tri[base + 0 * 65536] = t0;
            tri[base + 1 * 65536] = t1;
            tri[base + 2 * 65536] = t2;
            tri[base + 3 * 65536] = t3;
        }
    }
    __syncthreads();

    const int lane = tid & 63;
    const int t = tid >> 6;                 // tensor 0=q 1=k 2=vT 3=g
    const int lr = lane & 15, kg = lane >> 4;
    const int i_ = p0 >> 8;
    const int j0 = p0 & 255;

    const ushort_t* whb = Wc_hi + ((size_t)(t * 128 + lr)) * CZ + kg * 8;
    const ushort_t* wlb = Wc_lo + ((size_t)(t * 128 + lr)) * CZ + kg * 8;

    #pragma unroll
    for (int np = 0; np < 2; np++) {
        f32x4 acc[4][4];
        #pragma unroll
        for (int a = 0; a < 4; a++)
            #pragma unroll
            for (int b = 0; b < 4; b++) acc[a][b] = (f32x4){0.f, 0.f, 0.f, 0.f};

        #pragma unroll
        for (int ks = 0; ks < 4; ks++) {
            bf16x8 xh[4], xl[4];
            #pragma unroll
            for (int mt = 0; mt < 4; mt++) {
                xh[mt] = *(bf16x8*)&sXh[ks >> 1][SX(mt * 16 + lr, (ks & 1) * 4 + kg)];
                xl[mt] = *(bf16x8*)&sXl[ks >> 1][SX(mt * 16 + lr, (ks & 1) * 4 + kg)];
            }
            #pragma unroll
            for (int nt = 0; nt < 4; nt++) {
                int n = np * 64 + nt * 16;
                bf16x8 wh = *(const bf16x8*)(whb + (size_t)n * CZ + ks * 32);
                bf16x8 wl = *(const bf16x8*)(wlb + (size_t)n * CZ + ks * 32);
                if (t == 2) {
                    #pragma unroll
                    for (int mt = 0; mt < 4; mt++) {
                        acc[mt][nt] = __builtin_amdgcn_mfma_f32_16x16x32_bf16(xh[mt], wh, acc[mt][nt], 0, 0, 0);
                        acc[mt][nt] = __builtin_amdgcn_mfma_f32_16x16x32_bf16(xl[mt], wh, acc[mt][nt], 0, 0, 0);
                        acc[mt][nt] = __builtin_amdgcn_mfma_f32_16x16x32_bf16(xh[mt], wl, acc[mt][nt], 0, 0, 0);
                    }
                } else {
                    #pragma unroll
                    for (int mt = 0; mt < 4; mt++) {
                        acc[nt][mt] = __builtin_amdgcn_mfma_f32_16x16x32_bf16(wh, xh[mt], acc[nt][mt], 0, 0, 0);
                        acc[nt][mt] = __builtin_amdgcn_mfma_f32_16x16x32_bf16(wh, xl[mt], acc[nt][mt], 0, 0, 0);
                        acc[nt][mt] = __builtin_amdgcn_mfma_f32_16x16x32_bf16(wl, xh[mt], acc[nt][mt], 0, 0, 0);
                    }
                }
            }
        }

        if (t == 2) {
            #pragma unroll
            for (int mt = 0; mt < 4; mt++) {
                int j = j0 + mt * 16 + kg * 4;
                #pragma unroll
                for (int nt = 0; nt < 4; nt++) {
                    int c = np * 64 + nt * 16 + lr;
                    int h = c >> 5, d = c & 31;
                    size_t ihb = (size_t)((i_ << 2) + h) * 8192;
                    *(bf16x4*)(vto + ihb + (size_t)d * 256 + j) =
                        pack_bf4_rne(acc[mt][nt][0], acc[mt][nt][1],
                                     acc[mt][nt][2], acc[mt][nt][3]);
                }
            }
        } else {
            #pragma unroll
            for (int mt = 0; mt < 4; mt++) {
                int j = j0 + mt * 16 + lr;
                #pragma unroll
                for (int nt = 0; nt < 4; nt++) {
                    int c = np * 64 + nt * 16 + kg * 4;
                    int h = c >> 5, d = c & 31;
                    size_t base = (size_t)((i_ << 2) + h) * 8192 + (size_t)j * 32 + d;
                    if (t == 0) {
                        *(bf16x4*)(qbo + base) = pack_bf4_rne(
                            acc[nt][mt][0] * SCALE, acc[nt][mt][1] * SCALE,
                            acc[nt][mt][2] * SCALE, acc[nt][mt][3] * SCALE);
                    } else if (t == 1) {
                        *(bf16x4*)(kbo + base) = pack_bf4_rne(
                            acc[nt][mt][0], acc[nt][mt][1],
                            acc[nt][mt][2], acc[nt][mt][3]);
                    } else {
                        ushort4 hv;
                        hv.x = f2h(acc[nt][mt][0]);
                        hv.y = f2h(acc[nt][mt][1]);
                        hv.z = f2h(acc[nt][mt][2]);
                        hv.w = f2h(acc[nt][mt][3]);
                        *(ushort4*)(gho + base) = hv;
                    }
                }
            }
        }
    }
}

// ---------------- K2: FUSED MFMA attention + out-projection ----------------
// block = (i, qc); 4 waves = 4 heads, 64 queries (q0 = qc*64) per wave.
// Attention: single-pass softmax, vT frags from global (L2-hot), no barriers.
// og (gated, /l) -> LDS bf16 hi/lo [64q][132-stride]; one barrier; out-proj:
// wave h computes out[64q][n in h*32..h*32+32) = og @ wo^T + bo.
__global__ __launch_bounds__(256, 4)
void attn_out_kernel(const ushort_t* __restrict__ qb,
                     const ushort_t* __restrict__ kb,
                     const ushort_t* __restrict__ vtb,
                     const ushort_t* __restrict__ gh,     // fp16
                     const float* __restrict__ tri,
                     const float* __restrict__ mask,
                     const float* __restrict__ bg,
                     const ushort_t* __restrict__ wo_hi,
                     const ushort_t* __restrict__ wo_lo,
                     const float* __restrict__ bo,
                     float* __restrict__ out) {
    __shared__ ushort_t sOgH[64 * 132];   // stride 132: conflict-free (66 dw rows)
    __shared__ ushort_t sOgL[64 * 132];

    const int bid = blockIdx.x;
    const int i = bid >> 2;
    const int qc = bid & 3;
    const int tid = threadIdx.x;
    const int lane = tid & 63;
    const int h = tid >> 6;               // wave = head
    const int lr = lane & 15;
    const int kg = lane >> 4;
    const int q0 = qc * 64;

    const size_t ih = (size_t)((i << 2) + h);
    const ushort_t* qp = qb + ih * 8192;
    const ushort_t* kp = kb + ih * 8192;
    const ushort_t* vp = vtb + ih * 8192;
    const float* mrow = mask + (i << 8);

    bf16x8 qf[4];
    #pragma unroll
    for (int nt = 0; nt < 4; nt++)
        qf[nt] = *(const bf16x8*)(qp + (size_t)(q0 + nt * 16 + lr) * 32 + kg * 8);

    float tl[4] = {0.f, 0.f, 0.f, 0.f};
    f32x4 o[4][2];
    #pragma unroll
    for (int nt = 0; nt < 4; nt++) {
        o[nt][0] = (f32x4){0.f, 0.f, 0.f, 0.f};
        o[nt][1] = (f32x4){0.f, 0.f, 0.f, 0.f};
    }

    #pragma unroll
    for (int kt = 0; kt < 4; kt++) {
        const int kt0 = kt * 64;
        #pragma unroll
        for (int mt = 0; mt < 4; mt++) {
            bf16x8 ka = *(const bf16x8*)(kp + (size_t)(kt0 + mt * 16 + lr) * 32 + kg * 8);
            const float* trib = tri + ((size_t)h << 16) +
                                ((((size_t)(kt * 16 + mt * 4 + qc)) * 4) * 64 +
                                 kg * 16 + lr) * 4;
            float4 trif[4];
            #pragma unroll
            for (int nt = 0; nt < 4; nt++)
                trif[nt] = *(const float4*)(trib + (size_t)nt * 256);
            float4 mq = *(const float4*)(mrow + kt0 + mt * 16 + kg * 4);
            float mb[4] = {(mq.x - 1.f) * 1e9f, (mq.y - 1.f) * 1e9f,
                           (mq.z - 1.f) * 1e9f, (mq.w - 1.f) * 1e9f};

            f32x4 st[4];
            #pragma unroll
            for (int nt = 0; nt < 4; nt++)
                st[nt] = __builtin_amdgcn_mfma_f32_16x16x32_bf16(
                    ka, qf[nt], (f32x4){0.f, 0.f, 0.f, 0.f}, 0, 0, 0);

            bf16x4 pa[4];
            #pragma unroll
            for (int nt = 0; nt < 4; nt++) {
                float p0 = trunc_bf(__expf(st[nt][0] + mb[0] + trif[nt].x));
                float p1 = trunc_bf(__expf(st[nt][1] + mb[1] + trif[nt].y));
                float p2 = trunc_bf(__expf(st[nt][2] + mb[2] + trif[nt].z));
                float p3 = trunc_bf(__expf(st[nt][3] + mb[3] + trif[nt].w));
                tl[nt] += (p0 + p1) + (p2 + p3);
                pa[nt] = pack_bf4(p0, p1, p2, p3);
            }
            // PV: vT frags straight from global (L2-resident row slice)
            #pragma unroll
            for (int dt = 0; dt < 2; dt++) {
                bf16x4 vb = *(const bf16x4*)(vp + (size_t)(dt * 16 + lr) * 256 +
                                             kt0 + mt * 16 + kg * 4);
                #pragma unroll
                for (int nt = 0; nt < 4; nt++)
                    o[nt][dt] = __builtin_amdgcn_mfma_f32_16x16x16bf16_1k(pa[nt], vb, o[nt][dt], 0, 0, 0);
            }
        }
    }

    // gate + /l -> og into LDS (bf16 hi/lo)
    float bgv0 = bg[(h << 5) + lr];
    float bgv1 = bg[(h << 5) + 16 + lr];
    #pragma unroll
    for (int nt = 0; nt < 4; nt++) {
        float t = tl[nt];
        t += __shfl_xor(t, 16);
        t += __shfl_xor(t, 32);
        float inv = 1.0f / t;
        #pragma unroll
        for (int r = 0; r < 4; r++) {
            float iv = __shfl(inv, kg * 4 + r, 16);
            int ql = nt * 16 + kg * 4 + r;            // local q in [0,64)
            #pragma unroll
            for (int dt = 0; dt < 2; dt++) {
                int d = dt * 16 + lr;
                float gate = sigmoidf_(h2f(gh[ih * 8192 + (size_t)(q0 + ql) * 32 + d]) +
                                       (dt ? bgv1 : bgv0));
                float val = o[nt][dt][r] * iv * gate;
                ushort_t vh = f2bf(val);
                int ofs = ql * 132 + (h << 5) + d;
                sOgH[ofs] = vh;
                sOgL[ofs] = f2bf(val - bf2f(vh));
            }
        }
    }
    __syncthreads();

    // out-proj: wave h -> n in [h*32, h*32+32); out[64q][32n] = og @ wo^T + bo
    const ushort_t* whb = wo_hi + (size_t)((h << 5) + lr) * CZ + kg * 8;
    const ushort_t* wlb = wo_lo + (size_t)((h << 5) + lr) * CZ + kg * 8;

    f32x4 acc[2][4];   // [nt][mt]
    #pragma unroll
    for (int a = 0; a < 2; a++)
        #pragma unroll
        for (int b = 0; b < 4; b++) acc[a][b] = (f32x4){0.f, 0.f, 0.f, 0.f};

    #pragma unroll
    for (int ks = 0; ks < 4; ks++) {
        bf16x8 ogh[4], ogl[4];
        #pragma unroll
        for (int mt = 0; mt < 4; mt++) {
            int off = (mt * 16 + lr) * 132 + ks * 32 + kg * 8;
            ogh[mt] = *(bf16x8*)&sOgH[off];
            ogl[mt] = *(bf16x8*)&sOgL[off];
        }
        #pragma unroll
        for (int nt = 0; nt < 2; nt++) {
            bf16x8 wh = *(const bf16x8*)(whb + (size_t)(nt * 16) * CZ + ks * 32);
            bf16x8 wl = *(const bf16x8*)(wlb + (size_t)(nt * 16) * CZ + ks * 32);
            #pragma unroll
            for (int mt = 0; mt < 4; mt++) {
                acc[nt][mt] = __builtin_amdgcn_mfma_f32_16x16x32_bf16(wh, ogh[mt], acc[nt][mt], 0, 0, 0);
                acc[nt][mt] = __builtin_amdgcn_mfma_f32_16x16x32_bf16(wl, ogh[mt], acc[nt][mt], 0, 0, 0);
                acc[nt][mt] = __builtin_amdgcn_mfma_f32_16x16x32_bf16(wh, ogl[mt], acc[nt][mt], 0, 0, 0);
            }
        }
    }

    #pragma unroll
    for (int mt = 0; mt < 4; mt++) {
        int q = q0 + mt * 16 + lr;
        #pragma unroll
        for (int nt = 0; nt < 2; nt++) {
            int n0 = (h << 5) + nt * 16 + kg * 4;
            float4 bv = *(const float4*)(bo + n0);
            float4 ov;
            ov.x = acc[nt][mt][0] + bv.x;
            ov.y = acc[nt][mt][1] + bv.y;
            ov.z = acc[nt][mt][2] + bv.z;
            ov.w = acc[nt][mt][3] + bv.w;
            *(float4*)(out + (size_t)((i << 8) + q) * CZ + n0) = ov;
        }
    }
}

extern "C" void kernel_launch(void* const* d_in, const int* in_sizes, int n_in,
                              void* d_out, int out_size, void* d_ws, size_t ws_size,
                              hipStream_t stream) {
    const float* x     = (const float*)d_in[0];
    const float* mask  = (const float*)d_in[1];
    const float* ln_g  = (const float*)d_in[2];
    const float* ln_b  = (const float*)d_in[3];
    const float* w_tri = (const float*)d_in[4];
    const float* wq    = (const float*)d_in[5];
    const float* wk    = (const float*)d_in[6];
    const float* wv    = (const float*)d_in[7];
    const float* wg    = (const float*)d_in[8];
    const float* bg    = (const float*)d_in[9];
    const float* wo    = (const float*)d_in[10];
    const float* bo    = (const float*)d_in[11];
    float* out = (float*)d_out;

    float* ws = (float*)d_ws;
    float* tri = ws;                              // 262144 f (pre-tiled)
    ushort_t* ghbuf = (ushort_t*)(ws + 262144);   // PSZ fp16
    ushort_t* qbuf  = ghbuf + PSZ;
    ushort_t* kbuf  = qbuf + PSZ;
    ushort_t* vtbuf = kbuf + PSZ;
    ushort_t* Wc_hi = vtbuf + PSZ;
    ushort_t* Wc_lo = Wc_hi + 65536;
    ushort_t* wo_hi = Wc_lo + 65536;
    ushort_t* wo_lo = wo_hi + 16384;

    convert_weights<<<320, 256, 0, stream>>>(wq, wk, wv, wg, wo, Wc_hi, Wc_lo, wo_hi, wo_lo);
    ln_qkvg_kernel<<<NPOS / 64, 256, 0, stream>>>(
        x, ln_g, ln_b, w_tri, Wc_hi, Wc_lo, tri, qbuf, kbuf, vtbuf, ghbuf);
    attn_out_kernel<<<NN * NH, 256, 0, stream>>>(
        qbuf, kbuf, vtbuf, ghbuf, tri, mask, bg, wo_hi, wo_lo, bo, out);
}